// Round 6
// baseline (103.577 us; speedup 1.0000x reference)
//
#include <hip/hip_runtime.h>
#include <hip/hip_bf16.h>

#define S_ 1024
#define H_ 16

typedef __attribute__((ext_vector_type(4))) float f32x4;
typedef __attribute__((ext_vector_type(8))) __bf16 bf16x8;
typedef __attribute__((ext_vector_type(4))) unsigned short ushort4v;

// native RTNE f32->bf16 (compiler emits v_cvt_pk_bf16_f32)
static __device__ __forceinline__ unsigned short f2bf(float f) {
  union { __bf16 h; unsigned short u; } x;
  x.h = (__bf16)f;
  return x.u;
}

static __device__ __forceinline__ void gload16(const void* g, void* l) {
  __builtin_amdgcn_global_load_lds(
      (const __attribute__((address_space(1))) void*)g,
      (__attribute__((address_space(3))) void*)l, 16, 0, 0);
}

// ---------------------------------------------------------------- convert f32 -> bf16
__global__ void k_cvt(const float* __restrict__ in, unsigned short* __restrict__ out, int n) {
  int i = (blockIdx.x * 256 + threadIdx.x) * 4;
  if (i >= n) return;
  f32x4 v = *(const f32x4*)(in + i);
  ushort4v o;
  for (int j = 0; j < 4; ++j) o[j] = f2bf(v[j]);
  *(ushort4v*)(out + i) = o;
}

// ------------------------------------------- transpose + convert: out[c][r] = bf16(in[r][c])
__global__ void k_tcvt(const float* __restrict__ in, unsigned short* __restrict__ out,
                       int R, int C) {
  __shared__ float t[32][33];
  int nc = C >> 5;
  int tr = blockIdx.x / nc, tc = blockIdx.x % nc;
  int r0 = tr * 32, c0 = tc * 32;
  int tx = threadIdx.x & 31, ty = threadIdx.x >> 5;  // ty 0..7
  for (int i = 0; i < 4; ++i)
    t[ty + i * 8][tx] = in[(size_t)(r0 + ty + i * 8) * C + c0 + tx];
  __syncthreads();
  for (int i = 0; i < 4; ++i)
    out[(size_t)(c0 + ty + i * 8) * R + r0 + tx] = f2bf(t[tx][ty + i * 8]);
}

// ======================================================= 256x256 8-phase-style GEMM (T2+T3+T4+T5)
// C = A * Bt^T + bias ; A [M][K], Bt [N][K] bf16 row-major; bf16 out.
// BK=32, 4-deep K-tile ring (128 KiB LDS), 8 waves (2M x 4N), per-wave C = 128x64.
// Stage tile t+3 during tile t; counted vmcnt(8) publish (in-flight = tiles t+2,t+3).
// QSC: scale output cols < 1024 by 0.125*log2(e) (q pre-scale for attn exp2).
template<int QSC>
__global__ __launch_bounds__(512, 2)
void k_gemm256(const unsigned short* __restrict__ A,
               const unsigned short* __restrict__ Bt,
               const float* __restrict__ bias,
               unsigned short* __restrict__ C,
               int M, int N, int K) {
  __shared__ __attribute__((aligned(16))) unsigned short As[4][256 * 32];
  __shared__ __attribute__((aligned(16))) unsigned short Bs[4][256 * 32];
  const int tid = threadIdx.x;
  const int lane = tid & 63;
  const int w = tid >> 6;                 // 0..7
  const int wr = w >> 2, wc = w & 3;      // 2 M-waves x 4 N-waves
  const int l15 = lane & 15, lh = lane >> 4;

  // bijective XCD swizzle (grid % 8 == 0): consecutive wg on one XCD share A-panels
  const int nTn = N >> 8;
  const int cpx = gridDim.x >> 3;
  const int wg = (blockIdx.x & 7) * cpx + (blockIdx.x >> 3);
  const int tm = wg / nTn, tn = wg % nTn;

  // staging: load j in {0,1}: u = j*512 + w*64 + lane ; LDS dest = u*16B (linear)
  // dest row = u/4, phys granule = lane%4 ; source granule = phys ^ (row&3)
  const int srow = w * 16 + (lane >> 2);                       // + j*128
  const int sg = ((lane & 3) ^ ((lane >> 2) & 3)) << 3;        // source col elem offset
  const unsigned short* Abase = A + (size_t)(tm * 256) * K;
  const unsigned short* Bbase = Bt + (size_t)(tn * 256) * K;

#define STAGE_UNIT(t, j)                                                              \
  do {                                                                                \
    const int r_ = srow + (j) * 128;                                                  \
    const size_t gk_ = (size_t)(t) * 32 + sg;                                         \
    gload16(Abase + (size_t)r_ * K + gk_, &As[(t) & 3][((j) * 128 + w * 16) * 32]);   \
    gload16(Bbase + (size_t)r_ * K + gk_, &Bs[(t) & 3][((j) * 128 + w * 16) * 32]);   \
  } while (0)

  f32x4 acc[8][4] = {};
  const int NT = K >> 5;   // 32

  // prologue: tiles 0,1,2 (12 gloads); publish tile 0 (tiles 1,2 in flight = 8 loads)
  STAGE_UNIT(0, 0); STAGE_UNIT(0, 1);
  STAGE_UNIT(1, 0); STAGE_UNIT(1, 1);
  STAGE_UNIT(2, 0); STAGE_UNIT(2, 1);
  asm volatile("s_waitcnt vmcnt(8)" ::: "memory");
  __builtin_amdgcn_s_barrier();

  const int gsw = (lh ^ (l15 & 3)) << 3;   // read-side granule swizzle (2-way max)

  for (int t = 0; t < NT; ++t) {
    const unsigned short* as = As[t & 3];
    const unsigned short* bs = Bs[t & 3];
    bf16x8 af[8], bfr[4];
    // ---- phase A: read B n0..3 + A m0..3 (8 ds_read_b128), stage unit0(t+3)
#pragma unroll
    for (int n = 0; n < 4; ++n)
      bfr[n] = *(const bf16x8*)&bs[(wc * 64 + n * 16 + l15) * 32 + gsw];
#pragma unroll
    for (int m = 0; m < 4; ++m)
      af[m] = *(const bf16x8*)&as[(wr * 128 + m * 16 + l15) * 32 + gsw];
    if (t + 3 < NT) STAGE_UNIT(t + 3, 0);
    __builtin_amdgcn_s_barrier();
    asm volatile("s_waitcnt lgkmcnt(0)" ::: "memory");
    __builtin_amdgcn_sched_barrier(0);
    __builtin_amdgcn_s_setprio(1);
#pragma unroll
    for (int m = 0; m < 4; ++m)
#pragma unroll
      for (int n = 0; n < 4; ++n)
        acc[m][n] = __builtin_amdgcn_mfma_f32_16x16x32_bf16(af[m], bfr[n], acc[m][n], 0, 0, 0);
    __builtin_amdgcn_s_setprio(0);
    __builtin_amdgcn_s_barrier();
    // ---- phase B: read A m4..7 (4 ds_read_b128), stage unit1(t+3)
#pragma unroll
    for (int m = 4; m < 8; ++m)
      af[m] = *(const bf16x8*)&as[(wr * 128 + m * 16 + l15) * 32 + gsw];
    if (t + 3 < NT) STAGE_UNIT(t + 3, 1);
    __builtin_amdgcn_s_barrier();
    asm volatile("s_waitcnt lgkmcnt(0)" ::: "memory");
    __builtin_amdgcn_sched_barrier(0);
    __builtin_amdgcn_s_setprio(1);
#pragma unroll
    for (int m = 4; m < 8; ++m)
#pragma unroll
      for (int n = 0; n < 4; ++n)
        acc[m][n] = __builtin_amdgcn_mfma_f32_16x16x32_bf16(af[m], bfr[n], acc[m][n], 0, 0, 0);
    __builtin_amdgcn_s_setprio(0);
    // publish tile t+1: leave tiles t+2, t+3 in flight (counted, never 0 mid-loop)
    if (t + 1 < NT) {
      if (t + 3 < NT)      asm volatile("s_waitcnt vmcnt(8)" ::: "memory");
      else if (t + 2 < NT) asm volatile("s_waitcnt vmcnt(4)" ::: "memory");
      else                 asm volatile("s_waitcnt vmcnt(0)" ::: "memory");
    }
    __builtin_amdgcn_s_barrier();
  }
#undef STAGE_UNIT

  // epilogue
  float bv[4];
#pragma unroll
  for (int n = 0; n < 4; ++n) bv[n] = bias[tn * 256 + wc * 64 + n * 16 + l15];
#pragma unroll
  for (int m = 0; m < 8; ++m)
#pragma unroll
    for (int r = 0; r < 4; ++r) {
      size_t grow = tm * 256 + wr * 128 + m * 16 + lh * 4 + r;
#pragma unroll
      for (int n = 0; n < 4; ++n) {
        int gcol = tn * 256 + wc * 64 + n * 16 + l15;
        float v = acc[m][n][r] + bv[n];
        if (QSC && gcol < 1024) v *= 0.18033688f;
        C[grow * N + gcol] = f2bf(v);
      }
    }
}

// ---------------------------------------------------------------- GEMM  C = A * Bt^T + bias
// (128x128 m97-structure; used for GEMM2 whose grid fills the chip at this tile size)
template<int OUTF32, int QSC>
__global__ __launch_bounds__(256, 2)
void k_gemm_bt(const unsigned short* __restrict__ A,
               const unsigned short* __restrict__ Bt,
               const float* __restrict__ bias,
               void* __restrict__ C,
               int M, int N, int K) {
  __shared__ __attribute__((aligned(16))) unsigned short As[128 * 64];
  __shared__ __attribute__((aligned(16))) unsigned short Bs[128 * 64];
  const int lane = threadIdx.x & 63;
  const int wv = threadIdx.x >> 6;
  const int nTn = N >> 7;
  const int tm = blockIdx.x / nTn;
  const int tn = blockIdx.x % nTn;
  const int r8 = lane >> 3, c8 = lane & 7;
  const int wr = (wv >> 1) * 64, wc = (wv & 1) * 64;
  const int l15 = lane & 15, lh = lane >> 4;

  f32x4 acc[4][4] = {};

  const int nkt = K >> 6;
  for (int kt = 0; kt < nkt; ++kt) {
    for (int i = 0; i < 4; ++i) {
      int row = wv * 32 + i * 8 + r8;
      int col = kt * 64 + ((c8 ^ (row & 7)) << 3);   // pre-swizzled global source
      gload16(A + (size_t)(tm * 128 + row) * K + col, &As[(wv * 32 + i * 8) * 64]);
      gload16(Bt + (size_t)(tn * 128 + row) * K + col, &Bs[(wv * 32 + i * 8) * 64]);
    }
    __syncthreads();
    __builtin_amdgcn_s_setprio(1);
    for (int kk = 0; kk < 2; ++kk) {
      bf16x8 af[4], bfr[4];
      for (int mi = 0; mi < 4; ++mi) {
        int row = wr + mi * 16 + l15;
        int col = (kk * 32 + lh * 8) ^ ((row & 7) << 3);  // swizzled read
        af[mi] = *(const bf16x8*)&As[row * 64 + col];
      }
      for (int ni = 0; ni < 4; ++ni) {
        int row = wc + ni * 16 + l15;
        int col = (kk * 32 + lh * 8) ^ ((row & 7) << 3);
        bfr[ni] = *(const bf16x8*)&Bs[row * 64 + col];
      }
      for (int mi = 0; mi < 4; ++mi)
        for (int ni = 0; ni < 4; ++ni)
          acc[mi][ni] = __builtin_amdgcn_mfma_f32_16x16x32_bf16(af[mi], bfr[ni], acc[mi][ni], 0, 0, 0);
    }
    __builtin_amdgcn_s_setprio(0);
    __syncthreads();
  }

  float bv[4];
  for (int ni = 0; ni < 4; ++ni) bv[ni] = bias[tn * 128 + wc + ni * 16 + l15];
  for (int mi = 0; mi < 4; ++mi)
    for (int r = 0; r < 4; ++r) {
      size_t grow = tm * 128 + wr + mi * 16 + lh * 4 + r;   // C/D: col=lane&15, row=(lane>>4)*4+reg
      for (int ni = 0; ni < 4; ++ni) {
        int gcol = tn * 128 + wc + ni * 16 + l15;
        float v = acc[mi][ni][r] + bv[ni];
        if (QSC && gcol < 1024) v *= 0.18033688f;  // 0.125*log2(e)
        if (OUTF32) ((float*)C)[grow * N + gcol] = v;
        else        ((unsigned short*)C)[grow * N + gcol] = f2bf(v);
      }
    }
}

// ------------------------------------------------- V reshape: Vt[b,h,d,s] from qkv[token][2048+h*64+d]
__global__ void k_vt(const unsigned short* __restrict__ qkv, unsigned short* __restrict__ Vt) {
  __shared__ __attribute__((aligned(16))) unsigned short t[64][72];
  int sb = blockIdx.x & 15;
  int h = (blockIdx.x >> 4) & 15;
  int b = blockIdx.x >> 8;
  int tr = threadIdx.x >> 2;      // 0..63
  int tc = threadIdx.x & 3;
  const unsigned short* src = qkv + (size_t)(b * S_ + sb * 64 + tr) * 3072 + 2048 + h * 64;
  bf16x8 rv[2];
  for (int half = 0; half < 2; ++half)
    rv[half] = *(const bf16x8*)(src + tc * 8 + half * 32);
  for (int half = 0; half < 2; ++half)
    *(bf16x8*)&t[tr][tc * 8 + half * 32] = rv[half];
  __syncthreads();
  for (int half = 0; half < 2; ++half) {
    int c0 = tc * 8 + half * 32;
    unsigned short ov[8];
    for (int j = 0; j < 8; ++j) ov[j] = t[c0 + j][tr];
    *(bf16x8*)(Vt + ((size_t)((b * H_ + h) * 64 + tr)) * S_ + sb * 64 + c0) = *(bf16x8*)ov;
  }
}

// ---------------------------------------------------------------- flash attention (paired q-tiles,
// no-max softmax + ones-MFMA row-sum + depth-3 counted-vmcnt pipeline + XCD-group swizzle).
// Q is pre-scaled by 0.125*log2(e) in GEMM1, so P = exp2(q.k) directly.
template<bool DIAG>
static __device__ __forceinline__ void attn_tile(
    const bf16x8 qf[2], const bf16x8 kf[2][4], const bf16x8 vf[2][4], bf16x8 onef,
    unsigned short* __restrict__ Pw, f32x4 o[4], f32x4* lacc,
    int q_lo, int k0, int l15, int lh) {
  f32x4 sc[4] = {};
  __builtin_amdgcn_s_setprio(1);
#pragma unroll
  for (int kk = 0; kk < 2; ++kk)
#pragma unroll
    for (int ni = 0; ni < 4; ++ni)
      sc[ni] = __builtin_amdgcn_mfma_f32_16x16x32_bf16(qf[kk], kf[kk][ni], sc[ni], 0, 0, 0);
  __builtin_amdgcn_s_setprio(0);
  // P = exp2(s'), masked entries exactly 0; pack to per-wave LDS (swizzled [16][64])
#pragma unroll
  for (int ni = 0; ni < 4; ++ni) {
    const int kpos = k0 + ni * 16 + l15;
#pragma unroll
    for (int r = 0; r < 4; ++r) {
      const int row = lh * 4 + r;
      float p = __builtin_amdgcn_exp2f(sc[ni][r]);
      if (DIAG && kpos > q_lo + row) p = 0.f;
      Pw[row * 64 + ((ni * 16 + l15) ^ ((row & 7) << 3))] = f2bf(p);
    }
  }
  // O += P*V ; l += P*ones
  __builtin_amdgcn_s_setprio(1);
#pragma unroll
  for (int kk = 0; kk < 2; ++kk) {
    int pcol = (kk * 32 + lh * 8) ^ ((l15 & 7) << 3);
    bf16x8 pf = *(const bf16x8*)&Pw[l15 * 64 + pcol];
#pragma unroll
    for (int ni = 0; ni < 4; ++ni)
      o[ni] = __builtin_amdgcn_mfma_f32_16x16x32_bf16(pf, vf[kk][ni], o[ni], 0, 0, 0);
    *lacc = __builtin_amdgcn_mfma_f32_16x16x32_bf16(pf, onef, *lacc, 0, 0, 0);
  }
  __builtin_amdgcn_s_setprio(0);
}

__global__ __launch_bounds__(256, 2)
void k_attn(const unsigned short* __restrict__ qkv,
            const unsigned short* __restrict__ Vt,
            unsigned short* __restrict__ ctx) {
  __shared__ __attribute__((aligned(16))) unsigned short Ks[3][64 * 64];
  __shared__ __attribute__((aligned(16))) unsigned short Vs[3][64 * 64];
  __shared__ __attribute__((aligned(16))) unsigned short Ps[4][16 * 64];
  const int lane = threadIdx.x & 63;
  const int wv = threadIdx.x >> 6;
  // XCD-group swizzle: all 8 q-pair blocks of one (b,h) land on the same XCD
  const int bid = blockIdx.x;
  const int p = bid >> 6;                 // 0..7
  const int g = ((bid >> 3) & 7) * 8 + (bid & 7);  // 0..63, g%8 == bid%8
  const int h = g & 15;
  const int b = g >> 4;
  const int qtA = p, qtB = 15 - p;
  const int r8 = lane >> 3, c8 = lane & 7;
  const int l15 = lane & 15, lh = lane >> 4;

  // stage QA into Ks[0], QB into Ks[1]; hoist fragments
  for (int i = 0; i < 2; ++i) {
    int row = wv * 16 + i * 8 + r8;
    int col = (c8 ^ (row & 7)) << 3;
    gload16(qkv + (size_t)(b * S_ + qtA * 64 + row) * 3072 + h * 64 + col, &Ks[0][(wv * 16 + i * 8) * 64]);
    gload16(qkv + (size_t)(b * S_ + qtB * 64 + row) * 3072 + h * 64 + col, &Ks[1][(wv * 16 + i * 8) * 64]);
  }
  __syncthreads();
  bf16x8 qfA[2], qfB[2];
#pragma unroll
  for (int kk = 0; kk < 2; ++kk) {
    int row = wv * 16 + l15;
    int col = (kk * 32 + lh * 8) ^ ((row & 7) << 3);
    qfA[kk] = *(const bf16x8*)&Ks[0][row * 64 + col];
    qfB[kk] = *(const bf16x8*)&Ks[1][row * 64 + col];
  }
  __syncthreads();   // hoist reads done in all waves before staging overwrites Ks

  bf16x8 onef;
#pragma unroll
  for (int j = 0; j < 8; ++j) onef[j] = (__bf16)1.0f;

  f32x4 oA[4] = {}, oB[4] = {}, lA = {}, lB = {};

  const int ntB = qtB + 1;   // >= 9

#define STAGE(t, j)                                                                     \
  do {                                                                                  \
    const int k0s = (t) * 64;                                                           \
    for (int i = 0; i < 2; ++i) {                                                       \
      int row = wv * 16 + i * 8 + r8;                                                   \
      int col = (c8 ^ (row & 7)) << 3;                                                  \
      gload16(qkv + (size_t)(b * S_ + k0s + row) * 3072 + 1024 + h * 64 + col,          \
              &Ks[j][(wv * 16 + i * 8) * 64]);                                          \
      gload16(Vt + (size_t)((b * H_ + h) * 64 + row) * S_ + k0s + col,                  \
              &Vs[j][(wv * 16 + i * 8) * 64]);                                          \
    }                                                                                   \
  } while (0)

  // prologue: stage tiles 0,1,2 (ntB >= 9 guarantees they exist)
  STAGE(0, 0);
  STAGE(1, 1);
  STAGE(2, 2);

  for (int kt = 0; kt < ntB; ++kt) {
    const int cb = kt % 3;
    if (kt + 2 < ntB)      asm volatile("s_waitcnt vmcnt(8)" ::: "memory");
    else if (kt + 1 < ntB) asm volatile("s_waitcnt vmcnt(4)" ::: "memory");
    else                   asm volatile("s_waitcnt vmcnt(0)" ::: "memory");
    __builtin_amdgcn_s_barrier();

    const int k0 = kt * 64;
    bf16x8 kf[2][4], vf[2][4];
#pragma unroll
    for (int kk = 0; kk < 2; ++kk)
#pragma unroll
      for (int ni = 0; ni < 4; ++ni) {
        int row = ni * 16 + l15;
        int col = (kk * 32 + lh * 8) ^ ((row & 7) << 3);
        kf[kk][ni] = *(const bf16x8*)&Ks[cb][row * 64 + col];
        vf[kk][ni] = *(const bf16x8*)&Vs[cb][row * 64 + col];
      }
    asm volatile("s_waitcnt lgkmcnt(0)" ::: "memory");  // my reads of buf[cb] complete
    __builtin_amdgcn_s_barrier();                        // all waves done reading buf[cb]
    if (kt + 3 < ntB) STAGE(kt + 3, cb);                 // refill the freed buffer

    if (kt == qtB)
      attn_tile<true >(qfB, kf, vf, onef, Ps[wv], oB, &lB, qtB * 64 + wv * 16, k0, l15, lh);
    else
      attn_tile<false>(qfB, kf, vf, onef, Ps[wv], oB, &lB, qtB * 64 + wv * 16, k0, l15, lh);
    if (kt < qtA)
      attn_tile<false>(qfA, kf, vf, onef, Ps[wv], oA, &lA, qtA * 64 + wv * 16, k0, l15, lh);
    else if (kt == qtA)
      attn_tile<true >(qfA, kf, vf, onef, Ps[wv], oA, &lA, qtA * 64 + wv * 16, k0, l15, lh);
  }
#undef STAGE

  // epilogue: O /= l, write ctx [token][h*64+d] bf16 for both tiles
#pragma unroll
  for (int r = 0; r < 4; ++r) {
    float invA = 1.f / lA[r], invB = 1.f / lB[r];
    size_t tokA = (size_t)b * S_ + qtA * 64 + wv * 16 + lh * 4 + r;
    size_t tokB = (size_t)b * S_ + qtB * 64 + wv * 16 + lh * 4 + r;
#pragma unroll
    for (int ni = 0; ni < 4; ++ni) {
      int col = h * 64 + ni * 16 + l15;
      ctx[tokA * 1024 + col] = f2bf(oA[ni][r] * invA);
      ctx[tokB * 1024 + col] = f2bf(oB[ni][r] * invB);
    }
  }
}

// ---------------------------------------------------------------- launch
extern "C" void kernel_launch(void* const* d_in, const int* in_sizes, int n_in,
                              void* d_out, int out_size, void* d_ws, size_t ws_size,
                              hipStream_t stream) {
  const float* hs    = (const float*)d_in[0];
  const float* att_w = (const float*)d_in[1];
  const float* att_b = (const float*)d_in[2];
  const float* out_w = (const float*)d_in[3];
  const float* out_b = (const float*)d_in[4];
  float* out = (float*)d_out;
  char* ws = (char*)d_ws;

  unsigned short* A   = (unsigned short*)(ws);                       // 8 MiB  (hs bf16 [4096][1024])
  unsigned short* W1t = (unsigned short*)(ws + (8ull  << 20));       // 6 MiB  (att_w^T [3072][1024])
  unsigned short* W2t = (unsigned short*)(ws + (14ull << 20));       // 2 MiB  (out_w^T [1024][1024])
  unsigned short* QKV = (unsigned short*)(ws + (16ull << 20));       // 24 MiB ([4096][3072])
  unsigned short* Vt  = (unsigned short*)(ws + (40ull << 20));       // 8 MiB  ([64][64][1024])
  unsigned short* CTX = (unsigned short*)(ws + (48ull << 20));       // 8 MiB  ([4096][1024])

  k_cvt<<<4096, 256, 0, stream>>>(hs, A, 4 * 1024 * 1024);
  k_tcvt<<<(1024 / 32) * (3072 / 32), 256, 0, stream>>>(att_w, W1t, 1024, 3072);
  k_tcvt<<<(1024 / 32) * (1024 / 32), 256, 0, stream>>>(out_w, W2t, 1024, 1024);
  k_gemm256<1><<<16 * 12, 512, 0, stream>>>(A, W1t, att_b, QKV, 4096, 3072, 1024);
  k_vt<<<4 * 16 * 16, 256, 0, stream>>>(QKV, Vt);
  k_attn<<<512, 256, 0, stream>>>(QKV, Vt, CTX);
  k_gemm_bt<1, 0><<<32 * 8, 256, 0, stream>>>(CTX, W2t, out_b, out, 4096, 1024, 1024);
}

// Round 7
// 91.934 us; speedup vs baseline: 1.1266x; 1.1266x over previous
//
#include <hip/hip_runtime.h>
#include <hip/hip_bf16.h>

#define S_ 1024
#define H_ 16

typedef __attribute__((ext_vector_type(4))) float f32x4;
typedef __attribute__((ext_vector_type(8))) __bf16 bf16x8;
typedef __attribute__((ext_vector_type(4))) unsigned short ushort4v;

// native RTNE f32->bf16 (compiler emits v_cvt_pk_bf16_f32)
static __device__ __forceinline__ unsigned short f2bf(float f) {
  union { __bf16 h; unsigned short u; } x;
  x.h = (__bf16)f;
  return x.u;
}

static __device__ __forceinline__ void gload16(const void* g, void* l) {
  __builtin_amdgcn_global_load_lds(
      (const __attribute__((address_space(1))) void*)g,
      (__attribute__((address_space(3))) void*)l, 16, 0, 0);
}

// ---------------------------------------------------------------- convert f32 -> bf16
__global__ void k_cvt(const float* __restrict__ in, unsigned short* __restrict__ out, int n) {
  int i = (blockIdx.x * 256 + threadIdx.x) * 4;
  if (i >= n) return;
  f32x4 v = *(const f32x4*)(in + i);
  ushort4v o;
  for (int j = 0; j < 4; ++j) o[j] = f2bf(v[j]);
  *(ushort4v*)(out + i) = o;
}

// ------------------------------------------- transpose + convert: out[c][r] = bf16(in[r][c])
__global__ void k_tcvt(const float* __restrict__ in, unsigned short* __restrict__ out,
                       int R, int C) {
  __shared__ float t[32][33];
  int nc = C >> 5;
  int tr = blockIdx.x / nc, tc = blockIdx.x % nc;
  int r0 = tr * 32, c0 = tc * 32;
  int tx = threadIdx.x & 31, ty = threadIdx.x >> 5;  // ty 0..7
  for (int i = 0; i < 4; ++i)
    t[ty + i * 8][tx] = in[(size_t)(r0 + ty + i * 8) * C + c0 + tx];
  __syncthreads();
  for (int i = 0; i < 4; ++i)
    out[(size_t)(c0 + ty + i * 8) * R + r0 + tx] = f2bf(t[tx][ty + i * 8]);
}

// ---------------------------------------------------------------- GEMM  C = A * Bt^T + bias
// A [M][K] bf16 row-major, Bt [N][K] bf16 row-major. 128x128 tile, BK=64, 4 waves.
// 92 VGPR / 32KB LDS -> __launch_bounds__(256,4): 4 blocks/CU co-resident; the extra
// TLP hides the vmcnt(0)+barrier drain that caps the 2-block m97 structure.
// QSC: scale output cols < 1024 (the q block) by 0.125*log2(e) so attn's exp2 is direct.
template<int OUTF32, int QSC>
__global__ __launch_bounds__(256, 4)
void k_gemm_bt(const unsigned short* __restrict__ A,
               const unsigned short* __restrict__ Bt,
               const float* __restrict__ bias,
               void* __restrict__ C,
               int M, int N, int K) {
  __shared__ __attribute__((aligned(16))) unsigned short As[128 * 64];
  __shared__ __attribute__((aligned(16))) unsigned short Bs[128 * 64];
  const int lane = threadIdx.x & 63;
  const int wv = threadIdx.x >> 6;
  const int nTn = N >> 7;
  const int tm = blockIdx.x / nTn;
  const int tn = blockIdx.x % nTn;
  const int r8 = lane >> 3, c8 = lane & 7;
  const int wr = (wv >> 1) * 64, wc = (wv & 1) * 64;
  const int l15 = lane & 15, lh = lane >> 4;

  f32x4 acc[4][4] = {};

  const int nkt = K >> 6;
  for (int kt = 0; kt < nkt; ++kt) {
    for (int i = 0; i < 4; ++i) {
      int row = wv * 32 + i * 8 + r8;
      int col = kt * 64 + ((c8 ^ (row & 7)) << 3);   // pre-swizzled global source
      gload16(A + (size_t)(tm * 128 + row) * K + col, &As[(wv * 32 + i * 8) * 64]);
      gload16(Bt + (size_t)(tn * 128 + row) * K + col, &Bs[(wv * 32 + i * 8) * 64]);
    }
    __syncthreads();
    __builtin_amdgcn_s_setprio(1);
    for (int kk = 0; kk < 2; ++kk) {
      bf16x8 af[4], bfr[4];
      for (int mi = 0; mi < 4; ++mi) {
        int row = wr + mi * 16 + l15;
        int col = (kk * 32 + lh * 8) ^ ((row & 7) << 3);  // swizzled read
        af[mi] = *(const bf16x8*)&As[row * 64 + col];
      }
      for (int ni = 0; ni < 4; ++ni) {
        int row = wc + ni * 16 + l15;
        int col = (kk * 32 + lh * 8) ^ ((row & 7) << 3);
        bfr[ni] = *(const bf16x8*)&Bs[row * 64 + col];
      }
      for (int mi = 0; mi < 4; ++mi)
        for (int ni = 0; ni < 4; ++ni)
          acc[mi][ni] = __builtin_amdgcn_mfma_f32_16x16x32_bf16(af[mi], bfr[ni], acc[mi][ni], 0, 0, 0);
    }
    __builtin_amdgcn_s_setprio(0);
    __syncthreads();
  }

  float bv[4];
  for (int ni = 0; ni < 4; ++ni) bv[ni] = bias[tn * 128 + wc + ni * 16 + l15];
  for (int mi = 0; mi < 4; ++mi)
    for (int r = 0; r < 4; ++r) {
      size_t grow = tm * 128 + wr + mi * 16 + lh * 4 + r;   // C/D: col=lane&15, row=(lane>>4)*4+reg
      for (int ni = 0; ni < 4; ++ni) {
        int gcol = tn * 128 + wc + ni * 16 + l15;
        float v = acc[mi][ni][r] + bv[ni];
        if (QSC && gcol < 1024) v *= 0.18033688f;  // 0.125*log2(e)
        if (OUTF32) ((float*)C)[grow * N + gcol] = v;
        else        ((unsigned short*)C)[grow * N + gcol] = f2bf(v);
      }
    }
}

// ------------------------------------------------- V reshape: Vt[b,h,d,s] from qkv[token][2048+h*64+d]
__global__ void k_vt(const unsigned short* __restrict__ qkv, unsigned short* __restrict__ Vt) {
  __shared__ __attribute__((aligned(16))) unsigned short t[64][72];
  int sb = blockIdx.x & 15;
  int h = (blockIdx.x >> 4) & 15;
  int b = blockIdx.x >> 8;
  int tr = threadIdx.x >> 2;      // 0..63
  int tc = threadIdx.x & 3;
  const unsigned short* src = qkv + (size_t)(b * S_ + sb * 64 + tr) * 3072 + 2048 + h * 64;
  bf16x8 rv[2];
  for (int half = 0; half < 2; ++half)
    rv[half] = *(const bf16x8*)(src + tc * 8 + half * 32);
  for (int half = 0; half < 2; ++half)
    *(bf16x8*)&t[tr][tc * 8 + half * 32] = rv[half];
  __syncthreads();
  for (int half = 0; half < 2; ++half) {
    int c0 = tc * 8 + half * 32;
    unsigned short ov[8];
    for (int j = 0; j < 8; ++j) ov[j] = t[c0 + j][tr];
    *(bf16x8*)(Vt + ((size_t)((b * H_ + h) * 64 + tr)) * S_ + sb * 64 + c0) = *(bf16x8*)ov;
  }
}

// ---------------------------------------------------------------- flash attention (paired q-tiles,
// no-max softmax + ones-MFMA row-sum + depth-3 counted-vmcnt pipeline + XCD-group swizzle).
// Q is pre-scaled by 0.125*log2(e) in GEMM1, so P = exp2(q.k) directly.
template<bool DIAG>
static __device__ __forceinline__ void attn_tile(
    const bf16x8 qf[2], const bf16x8 kf[2][4], const bf16x8 vf[2][4], bf16x8 onef,
    unsigned short* __restrict__ Pw, f32x4 o[4], f32x4* lacc,
    int q_lo, int k0, int l15, int lh) {
  f32x4 sc[4] = {};
  __builtin_amdgcn_s_setprio(1);
#pragma unroll
  for (int kk = 0; kk < 2; ++kk)
#pragma unroll
    for (int ni = 0; ni < 4; ++ni)
      sc[ni] = __builtin_amdgcn_mfma_f32_16x16x32_bf16(qf[kk], kf[kk][ni], sc[ni], 0, 0, 0);
  __builtin_amdgcn_s_setprio(0);
  // P = exp2(s'), masked entries exactly 0; pack to per-wave LDS (swizzled [16][64])
#pragma unroll
  for (int ni = 0; ni < 4; ++ni) {
    const int kpos = k0 + ni * 16 + l15;
#pragma unroll
    for (int r = 0; r < 4; ++r) {
      const int row = lh * 4 + r;
      float p = __builtin_amdgcn_exp2f(sc[ni][r]);
      if (DIAG && kpos > q_lo + row) p = 0.f;
      Pw[row * 64 + ((ni * 16 + l15) ^ ((row & 7) << 3))] = f2bf(p);
    }
  }
  // O += P*V ; l += P*ones
  __builtin_amdgcn_s_setprio(1);
#pragma unroll
  for (int kk = 0; kk < 2; ++kk) {
    int pcol = (kk * 32 + lh * 8) ^ ((l15 & 7) << 3);
    bf16x8 pf = *(const bf16x8*)&Pw[l15 * 64 + pcol];
#pragma unroll
    for (int ni = 0; ni < 4; ++ni)
      o[ni] = __builtin_amdgcn_mfma_f32_16x16x32_bf16(pf, vf[kk][ni], o[ni], 0, 0, 0);
    *lacc = __builtin_amdgcn_mfma_f32_16x16x32_bf16(pf, onef, *lacc, 0, 0, 0);
  }
  __builtin_amdgcn_s_setprio(0);
}

__global__ __launch_bounds__(256, 2)
void k_attn(const unsigned short* __restrict__ qkv,
            const unsigned short* __restrict__ Vt,
            unsigned short* __restrict__ ctx) {
  __shared__ __attribute__((aligned(16))) unsigned short Ks[3][64 * 64];
  __shared__ __attribute__((aligned(16))) unsigned short Vs[3][64 * 64];
  __shared__ __attribute__((aligned(16))) unsigned short Ps[4][16 * 64];
  const int lane = threadIdx.x & 63;
  const int wv = threadIdx.x >> 6;
  // XCD-group swizzle: all 8 q-pair blocks of one (b,h) land on the same XCD
  const int bid = blockIdx.x;
  const int p = bid >> 6;                 // 0..7
  const int g = ((bid >> 3) & 7) * 8 + (bid & 7);  // 0..63, g%8 == bid%8
  const int h = g & 15;
  const int b = g >> 4;
  const int qtA = p, qtB = 15 - p;
  const int r8 = lane >> 3, c8 = lane & 7;
  const int l15 = lane & 15, lh = lane >> 4;

  // stage QA into Ks[0], QB into Ks[1]; hoist fragments
  for (int i = 0; i < 2; ++i) {
    int row = wv * 16 + i * 8 + r8;
    int col = (c8 ^ (row & 7)) << 3;
    gload16(qkv + (size_t)(b * S_ + qtA * 64 + row) * 3072 + h * 64 + col, &Ks[0][(wv * 16 + i * 8) * 64]);
    gload16(qkv + (size_t)(b * S_ + qtB * 64 + row) * 3072 + h * 64 + col, &Ks[1][(wv * 16 + i * 8) * 64]);
  }
  __syncthreads();
  bf16x8 qfA[2], qfB[2];
#pragma unroll
  for (int kk = 0; kk < 2; ++kk) {
    int row = wv * 16 + l15;
    int col = (kk * 32 + lh * 8) ^ ((row & 7) << 3);
    qfA[kk] = *(const bf16x8*)&Ks[0][row * 64 + col];
    qfB[kk] = *(const bf16x8*)&Ks[1][row * 64 + col];
  }
  __syncthreads();   // hoist reads done in all waves before staging overwrites Ks

  bf16x8 onef;
#pragma unroll
  for (int j = 0; j < 8; ++j) onef[j] = (__bf16)1.0f;

  f32x4 oA[4] = {}, oB[4] = {}, lA = {}, lB = {};

  const int ntB = qtB + 1;   // >= 9

#define STAGE(t, j)                                                                     \
  do {                                                                                  \
    const int k0s = (t) * 64;                                                           \
    for (int i = 0; i < 2; ++i) {                                                       \
      int row = wv * 16 + i * 8 + r8;                                                   \
      int col = (c8 ^ (row & 7)) << 3;                                                  \
      gload16(qkv + (size_t)(b * S_ + k0s + row) * 3072 + 1024 + h * 64 + col,          \
              &Ks[j][(wv * 16 + i * 8) * 64]);                                          \
      gload16(Vt + (size_t)((b * H_ + h) * 64 + row) * S_ + k0s + col,                  \
              &Vs[j][(wv * 16 + i * 8) * 64]);                                          \
    }                                                                                   \
  } while (0)

  // prologue: stage tiles 0,1,2 (ntB >= 9 guarantees they exist)
  STAGE(0, 0);
  STAGE(1, 1);
  STAGE(2, 2);

  for (int kt = 0; kt < ntB; ++kt) {
    const int cb = kt % 3;
    if (kt + 2 < ntB)      asm volatile("s_waitcnt vmcnt(8)" ::: "memory");
    else if (kt + 1 < ntB) asm volatile("s_waitcnt vmcnt(4)" ::: "memory");
    else                   asm volatile("s_waitcnt vmcnt(0)" ::: "memory");
    __builtin_amdgcn_s_barrier();

    const int k0 = kt * 64;
    bf16x8 kf[2][4], vf[2][4];
#pragma unroll
    for (int kk = 0; kk < 2; ++kk)
#pragma unroll
      for (int ni = 0; ni < 4; ++ni) {
        int row = ni * 16 + l15;
        int col = (kk * 32 + lh * 8) ^ ((row & 7) << 3);
        kf[kk][ni] = *(const bf16x8*)&Ks[cb][row * 64 + col];
        vf[kk][ni] = *(const bf16x8*)&Vs[cb][row * 64 + col];
      }
    asm volatile("s_waitcnt lgkmcnt(0)" ::: "memory");  // my reads of buf[cb] complete
    __builtin_amdgcn_s_barrier();                        // all waves done reading buf[cb]
    if (kt + 3 < ntB) STAGE(kt + 3, cb);                 // refill the freed buffer

    if (kt == qtB)
      attn_tile<true >(qfB, kf, vf, onef, Ps[wv], oB, &lB, qtB * 64 + wv * 16, k0, l15, lh);
    else
      attn_tile<false>(qfB, kf, vf, onef, Ps[wv], oB, &lB, qtB * 64 + wv * 16, k0, l15, lh);
    if (kt < qtA)
      attn_tile<false>(qfA, kf, vf, onef, Ps[wv], oA, &lA, qtA * 64 + wv * 16, k0, l15, lh);
    else if (kt == qtA)
      attn_tile<true >(qfA, kf, vf, onef, Ps[wv], oA, &lA, qtA * 64 + wv * 16, k0, l15, lh);
  }
#undef STAGE

  // epilogue: O /= l, write ctx [token][h*64+d] bf16 for both tiles
#pragma unroll
  for (int r = 0; r < 4; ++r) {
    float invA = 1.f / lA[r], invB = 1.f / lB[r];
    size_t tokA = (size_t)b * S_ + qtA * 64 + wv * 16 + lh * 4 + r;
    size_t tokB = (size_t)b * S_ + qtB * 64 + wv * 16 + lh * 4 + r;
#pragma unroll
    for (int ni = 0; ni < 4; ++ni) {
      int col = h * 64 + ni * 16 + l15;
      ctx[tokA * 1024 + col] = f2bf(oA[ni][r] * invA);
      ctx[tokB * 1024 + col] = f2bf(oB[ni][r] * invB);
    }
  }
}

// ---------------------------------------------------------------- launch
extern "C" void kernel_launch(void* const* d_in, const int* in_sizes, int n_in,
                              void* d_out, int out_size, void* d_ws, size_t ws_size,
                              hipStream_t stream) {
  const float* hs    = (const float*)d_in[0];
  const float* att_w = (const float*)d_in[1];
  const float* att_b = (const float*)d_in[2];
  const float* out_w = (const float*)d_in[3];
  const float* out_b = (const float*)d_in[4];
  float* out = (float*)d_out;
  char* ws = (char*)d_ws;

  unsigned short* A   = (unsigned short*)(ws);                       // 8 MiB  (hs bf16 [4096][1024])
  unsigned short* W1t = (unsigned short*)(ws + (8ull  << 20));       // 6 MiB  (att_w^T [3072][1024])
  unsigned short* W2t = (unsigned short*)(ws + (14ull << 20));       // 2 MiB  (out_w^T [1024][1024])
  unsigned short* QKV = (unsigned short*)(ws + (16ull << 20));       // 24 MiB ([4096][3072])
  unsigned short* Vt  = (unsigned short*)(ws + (40ull << 20));       // 8 MiB  ([64][64][1024])
  unsigned short* CTX = (unsigned short*)(ws + (48ull << 20));       // 8 MiB  ([4096][1024])

  k_cvt<<<4096, 256, 0, stream>>>(hs, A, 4 * 1024 * 1024);
  k_tcvt<<<(1024 / 32) * (3072 / 32), 256, 0, stream>>>(att_w, W1t, 1024, 3072);
  k_tcvt<<<(1024 / 32) * (1024 / 32), 256, 0, stream>>>(out_w, W2t, 1024, 1024);
  k_gemm_bt<0, 1><<<32 * 24, 256, 0, stream>>>(A, W1t, att_b, QKV, 4096, 3072, 1024);
  k_vt<<<4 * 16 * 16, 256, 0, stream>>>(QKV, Vt);
  k_attn<<<512, 256, 0, stream>>>(QKV, Vt, CTX);
  k_gemm_bt<1, 0><<<32 * 8, 256, 0, stream>>>(CTX, W2t, out_b, out, 4096, 1024, 1024);
}